// Round 1
// baseline (586.405 us; speedup 1.0000x reference)
//
#include <hip/hip_runtime.h>
#include <cstddef>

// Problem constants (from reference): N=Q=16384, D=3.
// d_out layout (flat float32, outputs concatenated in return order):
//   [0, Q*N)              mask  (0.0 / 1.0)
//   [Q*N, Q*N + Q + 1)    row_splits (exclusive-scan of counts, as float)
//   [Q*N + Q + 1, end)    weights (sqdist where mask else 0)

namespace {

constexpr int NPTS = 16384;
constexpr int NQ   = 16384;
constexpr int QB   = 8;     // queries per block
constexpr int TPB  = 256;   // threads per block
constexpr int VEC  = 4;     // points per thread per iteration
constexpr int ITERS = NPTS / (TPB * VEC); // 16

__device__ __forceinline__ float mulrn(float a, float b) { return __fmul_rn(a, b); }
__device__ __forceinline__ float addrn(float a, float b) { return __fadd_rn(a, b); }

__global__ __launch_bounds__(TPB) void ball_kernel(
    const float* __restrict__ data,      // [N,3]
    const float* __restrict__ queries,   // [Q,3]
    const float* __restrict__ radius_p,  // [1]
    float* __restrict__ out,
    int* __restrict__ counts)            // [Q] in workspace
{
    const int tid = threadIdx.x;
    const int q0  = blockIdx.x * QB;

    __shared__ float qs[QB * 3];
    __shared__ int   scnt[QB];
    if (tid < QB * 3) qs[tid] = queries[(size_t)q0 * 3 + tid];
    if (tid < QB)     scnt[tid] = 0;
    __syncthreads();

    const float r  = radius_p[0];
    const float r2 = mulrn(r, r);

    float qx[QB], qy[QB], qz[QB], q2v[QB];
#pragma unroll
    for (int i = 0; i < QB; ++i) {
        qx[i] = qs[3 * i + 0];
        qy[i] = qs[3 * i + 1];
        qz[i] = qs[3 * i + 2];
        q2v[i] = addrn(addrn(mulrn(qx[i], qx[i]), mulrn(qy[i], qy[i])),
                       mulrn(qz[i], qz[i]));
    }

    int cnt[QB];
#pragma unroll
    for (int i = 0; i < QB; ++i) cnt[i] = 0;

    float* __restrict__ mask = out;
    float* __restrict__ wts  = out + ((size_t)NQ * NPTS + NQ + 1);

    for (int it = 0; it < ITERS; ++it) {
        const int nb = (it * TPB + tid) * VEC;
        // 4 consecutive points = 12 floats = 3 aligned float4 loads
        const float4 dA = *reinterpret_cast<const float4*>(data + (size_t)nb * 3 + 0);
        const float4 dB = *reinterpret_cast<const float4*>(data + (size_t)nb * 3 + 4);
        const float4 dC = *reinterpret_cast<const float4*>(data + (size_t)nb * 3 + 8);
        const float dx[VEC] = {dA.x, dA.w, dB.z, dC.y};
        const float dy[VEC] = {dA.y, dB.x, dB.w, dC.z};
        const float dz[VEC] = {dA.z, dB.y, dC.x, dC.w};
        float d2[VEC];
#pragma unroll
        for (int j = 0; j < VEC; ++j)
            d2[j] = addrn(addrn(mulrn(dx[j], dx[j]), mulrn(dy[j], dy[j])),
                          mulrn(dz[j], dz[j]));

#pragma unroll
        for (int q = 0; q < QB; ++q) {
            float m[VEC], w[VEC];
#pragma unroll
            for (int j = 0; j < VEC; ++j) {
                const float dot = addrn(addrn(mulrn(qx[q], dx[j]), mulrn(qy[q], dy[j])),
                                        mulrn(qz[q], dz[j]));
                float sq = __fsub_rn(addrn(q2v[q], d2[j]), mulrn(2.0f, dot));
                sq = fmaxf(sq, 0.0f);
                const bool in = (sq <= r2);
                m[j] = in ? 1.0f : 0.0f;
                w[j] = in ? sq : 0.0f;
                cnt[q] += in ? 1 : 0;
            }
            const size_t base = (size_t)(q0 + q) * NPTS + nb;
            *reinterpret_cast<float4*>(mask + base) = make_float4(m[0], m[1], m[2], m[3]);
            // weights region starts at odd element offset -> not float4-alignable
            wts[base + 0] = w[0];
            wts[base + 1] = w[1];
            wts[base + 2] = w[2];
            wts[base + 3] = w[3];
        }
    }

    // Block reduction of per-thread counts (wave shfl, then LDS atomics).
#pragma unroll
    for (int q = 0; q < QB; ++q) {
        int v = cnt[q];
        for (int off = 32; off >= 1; off >>= 1) v += __shfl_down(v, off);
        if ((tid & 63) == 0) atomicAdd(&scnt[q], v);
    }
    __syncthreads();
    if (tid < QB) counts[q0 + tid] = scnt[tid];
}

constexpr int STPB  = 256;
constexpr int CHUNK = NQ / STPB; // 64

__global__ __launch_bounds__(STPB) void scan_kernel(
    const int* __restrict__ counts, float* __restrict__ out)
{
    __shared__ int sums[STPB];
    const int tid  = threadIdx.x;
    const int base = tid * CHUNK;

    int s = 0;
    for (int i = 0; i < CHUNK; ++i) s += counts[base + i];
    sums[tid] = s;
    __syncthreads();

    // Hillis-Steele inclusive scan over 256 partial sums
    for (int off = 1; off < STPB; off <<= 1) {
        int v = 0;
        if (tid >= off) v = sums[tid - off];
        __syncthreads();
        sums[tid] += v;
        __syncthreads();
    }

    int run = (tid == 0) ? 0 : sums[tid - 1];
    float* rs = out + (size_t)NQ * NPTS;
    if (tid == 0) rs[0] = 0.0f;
    for (int i = 0; i < CHUNK; ++i) {
        run += counts[base + i];
        rs[base + i + 1] = (float)run;
    }
}

} // namespace

extern "C" void kernel_launch(void* const* d_in, const int* in_sizes, int n_in,
                              void* d_out, int out_size, void* d_ws, size_t ws_size,
                              hipStream_t stream) {
    const float* data    = (const float*)d_in[0];
    const float* queries = (const float*)d_in[1];
    const float* radius  = (const float*)d_in[2];
    float* out  = (float*)d_out;
    int* counts = (int*)d_ws;

    hipLaunchKernelGGL(ball_kernel, dim3(NQ / QB), dim3(TPB), 0, stream,
                       data, queries, radius, out, counts);
    hipLaunchKernelGGL(scan_kernel, dim3(1), dim3(STPB), 0, stream, counts, out);
}